// Round 8
// baseline (3882.756 us; speedup 1.0000x reference)
//
#include <hip/hip_runtime.h>

#define DD 800
#define HH 800
#define BB 64
#define TT 48
#define N3H 2400
#define VV 32000
#define MR (TT*BB)   // 3072 rows, time-major (t*BB + b)
#define NBLK 25      // scan blocks: 25 x 32 H-columns

typedef __attribute__((ext_vector_type(8))) short bf16x8;
typedef __attribute__((ext_vector_type(4))) float f32x4;
typedef __attribute__((ext_vector_type(4))) float float4v;
typedef __attribute__((address_space(1))) const unsigned int as1_uint;
typedef __attribute__((address_space(3))) unsigned int as3_uint;

__device__ __forceinline__ short f2bf(float f) {
  unsigned int u = __builtin_bit_cast(unsigned int, f);
  u = (u + 0x7fffu + ((u >> 16) & 1u)) >> 16;
  return (short)(unsigned short)u;
}

__device__ __forceinline__ void gload16(const void* g, void* l) {
  __builtin_amdgcn_global_load_lds((as1_uint*)g, (as3_uint*)l, 16, 0, 0);
}

// device-coherent stores: write-through to IC (bypass L1/L2) -> fence-free visibility
__device__ __forceinline__ void storef_cc(float* p, float v) {
  asm volatile("global_store_dword %0, %1, off sc0 sc1" :: "v"(p), "v"(v));
}
__device__ __forceinline__ void stores_cc(short* p, int v) {
  asm volatile("global_store_short %0, %1, off sc0 sc1" :: "v"(p), "v"(v));
}

// ---------------- transpose + cast fp32 [K][N] -> bf16 [N][K] ----------------
__global__ void k_cast_transpose(const float* __restrict__ src, short* __restrict__ dst,
                                 int K, int N) {
  __shared__ float tile[32][33];
  int n0 = blockIdx.x * 32, k0 = blockIdx.y * 32;
  int tx = threadIdx.x, ty = threadIdx.y;   // (32,8)
#pragma unroll
  for (int i = 0; i < 4; ++i) {
    int k = k0 + ty + i * 8, n = n0 + tx;
    if (k < K && n < N) tile[ty + i * 8][tx] = src[(size_t)k * N + n];
  }
  __syncthreads();
#pragma unroll
  for (int i = 0; i < 4; ++i) {
    int n = n0 + ty + i * 8, k = k0 + tx;
    if (n < N && k < K) dst[(size_t)n * K + k] = f2bf(tile[tx][ty + i * 8]);
  }
}

// ---------------- gather embedding rows -> bf16, time-major ----------------
__global__ void k_gather(const int* __restrict__ ids, const float* __restrict__ emb,
                         short* __restrict__ out) {
  int r = blockIdx.x;            // r = t*BB + b
  int t = r >> 6, b = r & 63;
  int id = ids[b * TT + t];
  int i = threadIdx.x;
  if (i < 100) {
    const float* s = emb + (size_t)id * DD + i * 8;
    float4v v0 = *(const float4v*)s;
    float4v v1 = *(const float4v*)(s + 4);
    bf16x8 o;
    o[0] = f2bf(v0[0]); o[1] = f2bf(v0[1]); o[2] = f2bf(v0[2]); o[3] = f2bf(v0[3]);
    o[4] = f2bf(v1[0]); o[5] = f2bf(v1[1]); o[6] = f2bf(v1[2]); o[7] = f2bf(v1[3]);
    *(bf16x8*)(out + (size_t)r * DD + i * 8) = o;
  }
}

// ---------------- generic bf16 GEMM: C = A[M,K] * BT[N,K]^T + bias ----------------
// EPI 0: fp32 store (xg).  EPI 1: relu -> bf16 (fe).
// EPI 2: exp(v+bias), row-permuted store + per-wave row partial sums into Pp.
template <int EPI>
__global__ __launch_bounds__(256) void k_gemm(const short* __restrict__ A,
                                              const short* __restrict__ BT,
                                              const float* __restrict__ bias,
                                              float* __restrict__ Cf,
                                              short* __restrict__ Cb,
                                              float* __restrict__ Pp,
                                              int N, int K, int ldc) {
  __shared__ short lA[128 * 32];
  __shared__ short lB[128 * 32];
  const int tid = threadIdx.x, wid = tid >> 6, lane = tid & 63;
  const int m0 = blockIdx.y * 128, n0 = blockIdx.x * 128;
  const int wr = wid >> 1, wc = wid & 1;
  f32x4 acc[4][4] = {};
  for (int kt = 0; kt < K / 32; ++kt) {
    const int kb = kt * 32;
#pragma unroll
    for (int rr = 0; rr < 2; ++rr) {
      int s = rr * 256 + tid;
      gload16(A + (size_t)(m0 + (s >> 2)) * K + kb + (s & 3) * 8, (char*)lA + s * 16);
      gload16(BT + (size_t)(n0 + (s >> 2)) * K + kb + (s & 3) * 8, (char*)lB + s * 16);
    }
    __syncthreads();
    bf16x8 af[4], bfr[4];
#pragma unroll
    for (int i = 0; i < 4; ++i)
      af[i] = *(const bf16x8*)(lA + (wr * 64 + i * 16 + (lane & 15)) * 32 + (lane >> 4) * 8);
#pragma unroll
    for (int j = 0; j < 4; ++j)
      bfr[j] = *(const bf16x8*)(lB + (wc * 64 + j * 16 + (lane & 15)) * 32 + (lane >> 4) * 8);
#pragma unroll
    for (int i = 0; i < 4; ++i)
#pragma unroll
      for (int j = 0; j < 4; ++j)
        acc[i][j] = __builtin_amdgcn_mfma_f32_16x16x32_bf16(af[i], bfr[j], acc[i][j], 0, 0, 0);
    __syncthreads();
  }
  const int hi = lane >> 4, ccol = lane & 15;
  if (EPI == 2) {
#pragma unroll
    for (int i = 0; i < 4; ++i) {
      int row = m0 + wr * 64 + i * 16 + hi * 4;
#pragma unroll
      for (int rg = 0; rg < 4; ++rg) {
        int r = row + rg;
        int orow = (r & 63) * TT + (r >> 6);   // (t,b) -> (b,t)
        float part = 0.f;
#pragma unroll
        for (int j = 0; j < 4; ++j) {
          int col = n0 + wc * 64 + j * 16 + ccol;
          float v = __expf(acc[i][j][rg] + bias[col]);
          part += v;
          Cf[(size_t)orow * ldc + col] = v;
        }
#pragma unroll
        for (int mm = 1; mm < 16; mm <<= 1) part += __shfl_xor(part, mm);
        if (ccol == 0) Pp[(size_t)orow * 512 + blockIdx.x * 2 + wc] = part;
      }
    }
  } else {
#pragma unroll
    for (int i = 0; i < 4; ++i) {
      int row = m0 + wr * 64 + i * 16 + hi * 4;
#pragma unroll
      for (int j = 0; j < 4; ++j) {
        int col = n0 + wc * 64 + j * 16 + ccol;
        if (col >= N) continue;
        float bv = bias ? bias[col] : 0.f;
#pragma unroll
        for (int rg = 0; rg < 4; ++rg) {
          int r = row + rg;
          float v = acc[i][j][rg] + bv;
          if (EPI == 0) Cf[(size_t)r * ldc + col] = v;
          else          Cb[(size_t)r * ldc + col] = f2bf(v < 0.f ? 0.f : v);
        }
      }
    }
  }
}

// ------- per-wave 50-slot flag poll (one rt-domain = 25 blocks x 2 col-halves) -------
__device__ __forceinline__ void wait_flags(int* fl, int tgt, int lane) {
  bool ok;
  do {
    int v = tgt;
    if (lane < 2 * NBLK)
      v = __hip_atomic_load(&fl[lane], __ATOMIC_RELAXED, __HIP_MEMORY_SCOPE_AGENT);
    ok = __all(v - tgt >= 0);
    if (!ok) __builtin_amdgcn_s_sleep(1);
  } while (!ok);
  asm volatile("" ::: "memory");   // keep dependent plain loads below the poll
}

// ---------------- persistent GRU scan (one layer, 48 steps) ----------------
// 25 blocks x 512 threads. 4 INDEPENDENT rt-domains (16 batch rows each), 50 waves
// per domain (25 blocks x 2 col-halves). No __syncthreads in the loop: per-wave
// drain -> flag -> 50-slot poll. h + partials travel via sc1 (IC write-through);
// readers use plain cached loads at per-step fresh addresses. rt = wid>>1 puts 2
// different domains on each SIMD so poll stalls overlap with compute.
__global__ __launch_bounds__(512, 1) void k_scan(const float* __restrict__ xg,
                                                 const short* __restrict__ UT,
                                                 const float* __restrict__ br,
                                                 float* __restrict__ hF,
                                                 const short* __restrict__ hInit,
                                                 short* __restrict__ hSeq,
                                                 float* __restrict__ Sp,
                                                 int* __restrict__ flags, int ep0) {
  __shared__ short uT[96 * 808];     // [gate*32+lc][800], stride 808 (16B aligned)
  const int tid = threadIdx.x, wid = tid >> 6, lane = tid & 63;
  const int bid = blockIdx.x, c0 = bid * 32;
  const int rt = wid >> 1, ch = wid & 1;
  // stage U^T stripe: LDS row rr = g*32 + lc  <->  UT row g*800 + c0 + lc
  for (int idx = tid; idx < 96 * 100; idx += 512) {
    int rr = idx / 100, chk = idx % 100;
    int grow = (rr >> 5) * HH + c0 + (rr & 31);
    *(bf16x8*)(uT + rr * 808 + chk * 8) = *(const bf16x8*)(UT + (size_t)grow * HH + chk * 8);
  }
  const int hi = lane >> 4;
  const int ccol = lane & 15;
  const int lrow = hi * 4;                    // local row base within rt tile
  const int crow = rt * 16 + lrow;            // C-layout row base
  const int gcol = c0 + ch * 16 + ccol;       // global H column
  const int arow = rt * 16 + ccol;            // A-operand row
  const short* uz = uT + (0 * 32 + ch * 16 + ccol) * 808;
  const short* ur = uT + (1 * 32 + ch * 16 + ccol) * 808;
  const short* uh = uT + (2 * 32 + ch * 16 + ccol) * 808;
  int* fl = flags + rt * 64;
  const int slot = bid * 2 + ch;
  f32x4 hfr;
#pragma unroll
  for (int rg = 0; rg < 4; ++rg) hfr[rg] = hF[(crow + rg) * HH + gcol];
  const float brz = br[gcol], brr = br[HH + gcol], brh = br[2 * HH + gcol];
  float xzv[4], xrv[4], xhv[4];
#pragma unroll
  for (int rg = 0; rg < 4; ++rg) {
    const float* xrow = xg + ((size_t)(crow + rg)) * N3H;
    xzv[rg] = xrow[gcol];
    xrv[rg] = xrow[HH + gcol];
    xhv[rg] = xrow[2 * HH + gcol];
  }
  __syncthreads();   // uT staged (one-time; loop itself is sync-free)

#pragma unroll 1
  for (int t = 0; t < TT; ++t) {
    // ---- phase 1: cached loads of h(t-1) rows (fresh addresses), MFMA, exp ----
    const short* hPrev = (t == 0) ? hInit : hSeq + (size_t)(t - 1) * BB * HH;
    bf16x8 areg[25];
#pragma unroll
    for (int kt = 0; kt < 25; ++kt)
      areg[kt] = *(const bf16x8*)(hPrev + arow * HH + kt * 32 + hi * 8);
    f32x4 az = {}, ar = {}, ah = {};
#pragma unroll
    for (int kt = 0; kt < 25; ++kt) {
      const int o = kt * 32 + hi * 8;
      az = __builtin_amdgcn_mfma_f32_16x16x32_bf16(areg[kt], *(const bf16x8*)(uz + o), az, 0, 0, 0);
      ar = __builtin_amdgcn_mfma_f32_16x16x32_bf16(areg[kt], *(const bf16x8*)(ur + o), ar, 0, 0, 0);
      ah = __builtin_amdgcn_mfma_f32_16x16x32_bf16(areg[kt], *(const bf16x8*)(uh + o), ah, 0, 0, 0);
    }
    float ez[4], er[4], rh[4];
    float* sb = Sp + ((size_t)(t * 4 + rt) * 2 * NBLK + slot) * 32;
#pragma unroll
    for (int rg = 0; rg < 4; ++rg) {
      ez[rg] = __expf(xzv[rg] + az[rg] + brz);
      er[rg] = __expf(xrv[rg] + ar[rg] + brr);
      rh[rg] = ah[rg] + brh;
      float s1 = ez[rg], s2 = er[rg];
#pragma unroll
      for (int mm = 1; mm < 16; mm <<= 1) {
        s1 += __shfl_xor(s1, mm);
        s2 += __shfl_xor(s2, mm);
      }
      if (ccol == 0) {
        storef_cc(&sb[lrow + rg], s1);
        storef_cc(&sb[16 + lrow + rg], s2);
      }
    }
    asm volatile("s_waitcnt vmcnt(0)" ::: "memory");   // partials at IC
    if (lane == 0)
      __hip_atomic_store(&fl[slot], ep0 + 2 * t + 1, __ATOMIC_RELAXED, __HIP_MEMORY_SCOPE_AGENT);
    wait_flags(fl, ep0 + 2 * t + 1, lane);
    // ---- per-wave sum reduce: lane (half,sidx) sums 25 slots, combine across halves ----
    const int sidx = lane & 31, half = lane >> 5;
    const float* sd = Sp + ((size_t)(t * 4 + rt) * 2 * NBLK + half * NBLK) * 32 + sidx;
    float ps = 0.f;
#pragma unroll
    for (int k = 0; k < NBLK; ++k) ps += sd[k * 32];
    ps += __shfl_xor(ps, 32);
    // ---- phase 2: gates, h update, per-short sc1 stores ----
    short* hCur = hSeq + (size_t)t * BB * HH;
#pragma unroll
    for (int rg = 0; rg < 4; ++rg) {
      float zden = __shfl(ps, lrow + rg);
      float rden = __shfl(ps, 16 + lrow + rg);
      float z = ez[rg] / zden;
      float rr2 = er[rg] / rden;
      float hh = tanhf(xhv[rg] + rr2 * rh[rg]);
      float hn = z * hfr[rg] + (1.f - z) * hh;
      hfr[rg] = hn;
      stores_cc(&hCur[(crow + rg) * HH + gcol], (int)(unsigned short)f2bf(hn));
    }
    asm volatile("s_waitcnt vmcnt(0)" ::: "memory");   // h at IC
    if (lane == 0)
      __hip_atomic_store(&fl[slot], ep0 + 2 * t + 2, __ATOMIC_RELAXED, __HIP_MEMORY_SCOPE_AGENT);
    if (t + 1 < TT) {
#pragma unroll
      for (int rg = 0; rg < 4; ++rg) {   // prefetch next xg (overlaps the poll)
        const float* xrow = xg + ((size_t)(t + 1) * BB + crow + rg) * N3H;
        xzv[rg] = xrow[gcol];
        xrv[rg] = xrow[HH + gcol];
        xhv[rg] = xrow[2 * HH + gcol];
      }
      wait_flags(fl, ep0 + 2 * t + 2, lane);
    }
  }
#pragma unroll
  for (int rg = 0; rg < 4; ++rg) hF[(crow + rg) * HH + gcol] = hfr[rg];
}

// -------- normalize pass: sum 500 per-row partials, scale row (exp already stored) --------
__global__ __launch_bounds__(256) void k_softmax(float* __restrict__ out,
                                                 const float* __restrict__ Pp) {
  float* row = out + (size_t)blockIdx.x * VV;
  const float* pp = Pp + (size_t)blockIdx.x * 512;
  const int tid = threadIdx.x;
  __shared__ float red[4];
  float sum = 0.f;
  for (int i = tid; i < 500; i += 256) sum += pp[i];
#pragma unroll
  for (int s = 32; s >= 1; s >>= 1) sum += __shfl_xor(sum, s);
  if ((tid & 63) == 0) red[tid >> 6] = sum;
  __syncthreads();
  float inv = 1.f / (red[0] + red[1] + red[2] + red[3]);
  for (int i = tid * 4; i < VV; i += 1024) {
    float4v v = *(const float4v*)(row + i);
    v[0] *= inv; v[1] *= inv; v[2] *= inv; v[3] *= inv;
    *(float4v*)(row + i) = v;
  }
}

extern "C" void kernel_launch(void* const* d_in, const int* in_sizes, int n_in,
                              void* d_out, int out_size, void* d_ws, size_t ws_size,
                              hipStream_t stream) {
  (void)in_sizes; (void)n_in; (void)out_size; (void)ws_size;
  const int*   enc  = (const int*)d_in[0];
  const int*   dec  = (const int*)d_in[1];
  const float* embF = (const float*)d_in[2];
  const float* Wd1  = (const float*)d_in[3];
  const float* bd1  = (const float*)d_in[4];
  const float* Wf1  = (const float*)d_in[5];
  const float* Uf1  = (const float*)d_in[6];
  const float* bf1  = (const float*)d_in[7];
  const float* Wf2  = (const float*)d_in[8];
  const float* Uf2  = (const float*)d_in[9];
  const float* bf2  = (const float*)d_in[10];
  const float* embE = (const float*)d_in[11];
  const float* We1  = (const float*)d_in[12];
  const float* Ue1  = (const float*)d_in[13];
  const float* be1  = (const float*)d_in[14];
  const float* We2  = (const float*)d_in[15];
  const float* Ue2  = (const float*)d_in[16];
  const float* be2  = (const float*)d_in[17];
  const float* Wout = (const float*)d_in[18];
  const float* bout = (const float*)d_in[19];

  char* p = (char*)d_ws;
  auto alloc = [&](size_t bytes) { char* r = p; p += (bytes + 255) & ~(size_t)255; return r; };
  short* WdT = (short*)alloc((size_t)896 * 800 * 2);
  short* WTb[4]; short* UTb[4];
  for (int i = 0; i < 4; ++i) {
    WTb[i] = (short*)alloc((size_t)2432 * 800 * 2);
    UTb[i] = (short*)alloc((size_t)2400 * 800 * 2);
  }
  short* WoT = (short*)alloc((size_t)VV * 800 * 2);
  short* feA = (short*)alloc((size_t)MR * DD * 2);
  short* fe  = (short*)alloc((size_t)MR * DD * 2);
  short* ee  = (short*)alloc((size_t)MR * DD * 2);
  short* g1  = (short*)alloc((size_t)MR * HH * 2);
  short* g2s = (short*)alloc((size_t)MR * HH * 2);   // layer-1 hSeq scratch
  short* e1  = (short*)alloc((size_t)MR * HH * 2);
  short* e2  = (short*)alloc((size_t)MR * HH * 2);
  float* xg  = (float*)alloc((size_t)MR * N3H * 4);
  float* Ppart = (float*)alloc((size_t)MR * 512 * 4);
  float* Spart = (float*)alloc((size_t)4 * TT * 4 * 2 * NBLK * 32 * 4);  // [l][t][rt][slot][32]
  // --- zeroed-at-launch region: hF .. flags ---
  float* hF   = (float*)alloc((size_t)BB * HH * 4);
  short* hIn0 = (short*)alloc((size_t)BB * HH * 2);
  int* flags  = (int*)alloc((size_t)4 * 64 * 4);     // [rt][slot<50]

  size_t tail = (char*)(flags + 4 * 64) - (char*)hF;
  hipMemsetAsync(hF, 0, tail, stream);

  dim3 tb(32, 8);
  k_cast_transpose<<<dim3(25, 25), tb, 0, stream>>>(Wd1, WdT, 800, 800);
  const float* Ws[4] = {Wf1, Wf2, We1, We2};
  const float* Us[4] = {Uf1, Uf2, Ue1, Ue2};
  for (int i = 0; i < 4; ++i) {
    k_cast_transpose<<<dim3(75, 25), tb, 0, stream>>>(Ws[i], WTb[i], 800, 2400);
    k_cast_transpose<<<dim3(75, 25), tb, 0, stream>>>(Us[i], UTb[i], 800, 2400);
  }
  k_cast_transpose<<<dim3(1000, 25), tb, 0, stream>>>(Wout, WoT, 800, VV);
  k_gather<<<MR, 128, 0, stream>>>(enc, embF, feA);
  k_gather<<<MR, 128, 0, stream>>>(dec, embE, ee);
  // fe = relu(feA @ Wd1 + bd1)  -> bf16
  k_gemm<1><<<dim3(7, 24), 256, 0, stream>>>(feA, WdT, bd1, nullptr, fe, nullptr, 800, 800, 800);

  const float* bs[4] = {bf1, bf2, be1, be2};
  const short* Xs[4] = {fe, g1, ee, e1};
  short* hSeqL[4] = {g1, g2s, e1, e2};
  for (int l = 0; l < 4; ++l) {
    const short* hInit = (l == 0) ? hIn0 : hSeqL[l - 1] + (size_t)(TT - 1) * BB * HH;
    k_gemm<0><<<dim3(19, 24), 256, 0, stream>>>(Xs[l], WTb[l], bs[l], xg, nullptr, nullptr, N3H, 800, N3H);
    k_scan<<<NBLK, 512, 0, stream>>>(xg, UTb[l], bs[l] + N3H, hF, hInit, hSeqL[l],
                                     Spart + (size_t)l * TT * 4 * 2 * NBLK * 32,
                                     flags, l * 2 * TT);
  }
  // out = exp(e2 @ Wout + bout) -> d_out (row-permuted to [B,T,V]) + row partials
  k_gemm<2><<<dim3(250, 24), 256, 0, stream>>>(e2, WoT, bout, (float*)d_out, nullptr, Ppart, VV, 800, VV);
  k_softmax<<<MR, 256, 0, stream>>>((float*)d_out, Ppart);
}

// Round 10
// 2884.884 us; speedup vs baseline: 1.3459x; 1.3459x over previous
//
#include <hip/hip_runtime.h>

#define DD 800
#define HH 800
#define BB 64
#define TT 48
#define N3H 2400
#define VV 32000
#define MR (TT*BB)   // 3072 rows, time-major (t*BB + b)
#define NBLK 25      // scan workers: 25 x 32 H-columns (all on ONE XCD)

typedef __attribute__((ext_vector_type(8))) short bf16x8;
typedef __attribute__((ext_vector_type(4))) float f32x4;
typedef __attribute__((ext_vector_type(4))) float float4v;
typedef __attribute__((address_space(1))) const unsigned int as1_uint;
typedef __attribute__((address_space(3))) unsigned int as3_uint;

__device__ __forceinline__ short f2bf(float f) {
  unsigned int u = __builtin_bit_cast(unsigned int, f);
  u = (u + 0x7fffu + ((u >> 16) & 1u)) >> 16;
  return (short)(unsigned short)u;
}

__device__ __forceinline__ void gload16(const void* g, void* l) {
  __builtin_amdgcn_global_load_lds((as1_uint*)g, (as3_uint*)l, 16, 0, 0);
}

// L2-executed atomic read: atomic+0 (sc0 = return old) without sc1 stays in the
// XCD's L2 — never served from L1, reads the live L2 value. Poll primitive.
__device__ __forceinline__ int atomic_read_l2(int* p) {
  int v;
  int zero = 0;
  asm volatile("global_atomic_add %0, %1, %2, off sc0"
               : "=&v"(v) : "v"(p), "v"(zero) : "memory");
  asm volatile("s_waitcnt vmcnt(0)");
  return v;
}

// ---------------- transpose + cast fp32 [K][N] -> bf16 [N][K] ----------------
__global__ void k_cast_transpose(const float* __restrict__ src, short* __restrict__ dst,
                                 int K, int N) {
  __shared__ float tile[32][33];
  int n0 = blockIdx.x * 32, k0 = blockIdx.y * 32;
  int tx = threadIdx.x, ty = threadIdx.y;   // (32,8)
#pragma unroll
  for (int i = 0; i < 4; ++i) {
    int k = k0 + ty + i * 8, n = n0 + tx;
    if (k < K && n < N) tile[ty + i * 8][tx] = src[(size_t)k * N + n];
  }
  __syncthreads();
#pragma unroll
  for (int i = 0; i < 4; ++i) {
    int n = n0 + ty + i * 8, k = k0 + tx;
    if (n < N && k < K) dst[(size_t)n * K + k] = f2bf(tile[tx][ty + i * 8]);
  }
}

// ---------------- gather embedding rows -> bf16, time-major ----------------
__global__ void k_gather(const int* __restrict__ ids, const float* __restrict__ emb,
                         short* __restrict__ out) {
  int r = blockIdx.x;            // r = t*BB + b
  int t = r >> 6, b = r & 63;
  int id = ids[b * TT + t];
  int i = threadIdx.x;
  if (i < 100) {
    const float* s = emb + (size_t)id * DD + i * 8;
    float4v v0 = *(const float4v*)s;
    float4v v1 = *(const float4v*)(s + 4);
    bf16x8 o;
    o[0] = f2bf(v0[0]); o[1] = f2bf(v0[1]); o[2] = f2bf(v0[2]); o[3] = f2bf(v0[3]);
    o[4] = f2bf(v1[0]); o[5] = f2bf(v1[1]); o[6] = f2bf(v1[2]); o[7] = f2bf(v1[3]);
    *(bf16x8*)(out + (size_t)r * DD + i * 8) = o;
  }
}

// ---------------- generic bf16 GEMM: C = A[M,K] * BT[N,K]^T + bias ----------------
// EPI 0: fp32 store (xg).  EPI 1: relu -> bf16 (fe).
// EPI 2: exp(v+bias), row-permuted store + per-wave row partial sums into Pp.
template <int EPI>
__global__ __launch_bounds__(256) void k_gemm(const short* __restrict__ A,
                                              const short* __restrict__ BT,
                                              const float* __restrict__ bias,
                                              float* __restrict__ Cf,
                                              short* __restrict__ Cb,
                                              float* __restrict__ Pp,
                                              int N, int K, int ldc) {
  __shared__ short lA[128 * 32];
  __shared__ short lB[128 * 32];
  const int tid = threadIdx.x, wid = tid >> 6, lane = tid & 63;
  const int m0 = blockIdx.y * 128, n0 = blockIdx.x * 128;
  const int wr = wid >> 1, wc = wid & 1;
  f32x4 acc[4][4] = {};
  for (int kt = 0; kt < K / 32; ++kt) {
    const int kb = kt * 32;
#pragma unroll
    for (int rr = 0; rr < 2; ++rr) {
      int s = rr * 256 + tid;
      gload16(A + (size_t)(m0 + (s >> 2)) * K + kb + (s & 3) * 8, (char*)lA + s * 16);
      gload16(BT + (size_t)(n0 + (s >> 2)) * K + kb + (s & 3) * 8, (char*)lB + s * 16);
    }
    __syncthreads();
    bf16x8 af[4], bfr[4];
#pragma unroll
    for (int i = 0; i < 4; ++i)
      af[i] = *(const bf16x8*)(lA + (wr * 64 + i * 16 + (lane & 15)) * 32 + (lane >> 4) * 8);
#pragma unroll
    for (int j = 0; j < 4; ++j)
      bfr[j] = *(const bf16x8*)(lB + (wc * 64 + j * 16 + (lane & 15)) * 32 + (lane >> 4) * 8);
#pragma unroll
    for (int i = 0; i < 4; ++i)
#pragma unroll
      for (int j = 0; j < 4; ++j)
        acc[i][j] = __builtin_amdgcn_mfma_f32_16x16x32_bf16(af[i], bfr[j], acc[i][j], 0, 0, 0);
    __syncthreads();
  }
  const int hi = lane >> 4, ccol = lane & 15;
  if (EPI == 2) {
#pragma unroll
    for (int i = 0; i < 4; ++i) {
      int row = m0 + wr * 64 + i * 16 + hi * 4;
#pragma unroll
      for (int rg = 0; rg < 4; ++rg) {
        int r = row + rg;
        int orow = (r & 63) * TT + (r >> 6);   // (t,b) -> (b,t)
        float part = 0.f;
#pragma unroll
        for (int j = 0; j < 4; ++j) {
          int col = n0 + wc * 64 + j * 16 + ccol;
          float v = __expf(acc[i][j][rg] + bias[col]);
          part += v;
          Cf[(size_t)orow * ldc + col] = v;
        }
#pragma unroll
        for (int mm = 1; mm < 16; mm <<= 1) part += __shfl_xor(part, mm);
        if (ccol == 0) Pp[(size_t)orow * 512 + blockIdx.x * 2 + wc] = part;
      }
    }
  } else {
#pragma unroll
    for (int i = 0; i < 4; ++i) {
      int row = m0 + wr * 64 + i * 16 + hi * 4;
#pragma unroll
      for (int j = 0; j < 4; ++j) {
        int col = n0 + wc * 64 + j * 16 + ccol;
        if (col >= N) continue;
        float bv = bias ? bias[col] : 0.f;
#pragma unroll
        for (int rg = 0; rg < 4; ++rg) {
          int r = row + rg;
          float v = acc[i][j][rg] + bv;
          if (EPI == 0) Cf[(size_t)r * ldc + col] = v;
          else          Cb[(size_t)r * ldc + col] = f2bf(v < 0.f ? 0.f : v);
        }
      }
    }
  }
}

// ------- intra-XCD barrier: plain flag store (write-through -> shared L2),
// poll via L2-executed atomic (+0). Watchdog force-exits a broken spin so a
// wrong coherence model fails fast (bad absmax) instead of a 600s timeout. -------
__device__ __forceinline__ void bar_sync(int* flags, int ep, int tid, int role) {
  asm volatile("s_waitcnt vmcnt(0)" ::: "memory");   // payload acked in L2
  __syncthreads();
  if (tid == 0) flags[role * 16] = ep;               // plain store -> L2
  if (tid < 64) {
    bool ok;
    int guard = 0;
    do {
      int v = ep;
      if (tid < NBLK) v = atomic_read_l2(&flags[tid * 16]);
      ok = __all(v - ep >= 0);
      if (!ok) __builtin_amdgcn_s_sleep(2);
    } while (!ok && ++guard < (1 << 18));
    asm volatile("" ::: "memory");
  }
  __syncthreads();
}

// ---------------- persistent GRU scan (one layer, 48 steps) ----------------
// Launch 256 blocks (1/CU, all co-resident). Each block reads HW_REG_XCC_ID and
// registers on its XCD; first XCD reaching 25 registrants wins; its roles 0..24
// run the scan with the shared XCD L2 as coherence point; other blocks exit.
__global__ __launch_bounds__(512, 1) void k_scan(const float* __restrict__ xg,
                                                 const short* __restrict__ UT,
                                                 const float* __restrict__ br,
                                                 float* __restrict__ hF,
                                                 const short* __restrict__ hInit,
                                                 short* __restrict__ hSeq,
                                                 float* __restrict__ Sp,
                                                 int* __restrict__ flags, int ep0,
                                                 int* __restrict__ xreg) {
  __shared__ int sRole;
  if (threadIdx.x == 0) {
    int xcc;
    asm volatile("s_getreg_b32 %0, hwreg(HW_REG_XCC_ID)" : "=s"(xcc));
    xcc &= 7;
    int r = __hip_atomic_fetch_add(&xreg[xcc], 1, __ATOMIC_RELAXED, __HIP_MEMORY_SCOPE_AGENT);
    if (r == NBLK - 1) {
      int exp0 = 0;
      __hip_atomic_compare_exchange_strong(&xreg[8], &exp0, xcc + 1, __ATOMIC_RELAXED,
                                           __ATOMIC_RELAXED, __HIP_MEMORY_SCOPE_AGENT);
    }
    int w, guard = 0;
    do {
      w = __hip_atomic_load(&xreg[8], __ATOMIC_RELAXED, __HIP_MEMORY_SCOPE_AGENT);
      if (w == 0) __builtin_amdgcn_s_sleep(2);
    } while (w == 0 && ++guard < (1 << 20));
    sRole = (w != 0 && xcc == w - 1 && r < NBLK) ? r : -1;
  }
  __syncthreads();
  const int role = sRole;
  if (role < 0) return;

  __shared__ short uT[96 * 808];     // [gate*32+lc][800], stride 808 (16B aligned)
  __shared__ float sSum[128];
  __shared__ short hTile[64 * 32];   // staging for coalesced h stores
  const int tid = threadIdx.x, wid = tid >> 6, lane = tid & 63;
  const int c0 = role * 32;
  const int rt = wid & 3, ch = wid >> 2;
  // stage U^T stripe: LDS row rr = g*32 + lc  <->  UT row g*800 + c0 + lc
  for (int idx = tid; idx < 96 * 100; idx += 512) {
    int rr = idx / 100, chk = idx % 100;
    int grow = (rr >> 5) * HH + c0 + (rr & 31);
    *(bf16x8*)(uT + rr * 808 + chk * 8) = *(const bf16x8*)(UT + (size_t)grow * HH + chk * 8);
  }
  const int hi = lane >> 4;
  const int ccol = lane & 15;
  const int crow = rt * 16 + hi * 4;          // C-layout row base
  const int gcol = c0 + ch * 16 + ccol;       // global H column
  const int arow = rt * 16 + ccol;            // A-operand row
  const short* uz = uT + (0 * 32 + ch * 16 + ccol) * 808;
  const short* ur = uT + (1 * 32 + ch * 16 + ccol) * 808;
  const short* uh = uT + (2 * 32 + ch * 16 + ccol) * 808;
  f32x4 hfr;
#pragma unroll
  for (int rg = 0; rg < 4; ++rg) hfr[rg] = hF[(crow + rg) * HH + gcol];
  const float brz = br[gcol], brr = br[HH + gcol], brh = br[2 * HH + gcol];
  int ep = ep0;
  float xzv[4], xrv[4], xhv[4];
#pragma unroll
  for (int rg = 0; rg < 4; ++rg) {
    const float* xrow = xg + ((size_t)(crow + rg)) * N3H;
    xzv[rg] = xrow[gcol];
    xrv[rg] = xrow[HH + gcol];
    xhv[rg] = xrow[2 * HH + gcol];
  }
  __syncthreads();

#pragma unroll 1
  for (int t = 0; t < TT; ++t) {
    // ---- phase 1: plain loads of h(t-1) (fresh addrs -> L2 hit), MFMA, exp ----
    const short* hPrev = (t == 0) ? hInit : hSeq + (size_t)(t - 1) * BB * HH;
    bf16x8 areg[25];
#pragma unroll
    for (int kt = 0; kt < 25; ++kt)
      areg[kt] = *(const bf16x8*)(hPrev + arow * HH + kt * 32 + hi * 8);
    f32x4 az = {}, ar = {}, ah = {};
#pragma unroll
    for (int kt = 0; kt < 25; ++kt) {
      const int o = kt * 32 + hi * 8;
      az = __builtin_amdgcn_mfma_f32_16x16x32_bf16(areg[kt], *(const bf16x8*)(uz + o), az, 0, 0, 0);
      ar = __builtin_amdgcn_mfma_f32_16x16x32_bf16(areg[kt], *(const bf16x8*)(ur + o), ar, 0, 0, 0);
      ah = __builtin_amdgcn_mfma_f32_16x16x32_bf16(areg[kt], *(const bf16x8*)(uh + o), ah, 0, 0, 0);
    }
    float ez[4], er[4], rh[4];
    float* sb = Sp + (size_t)t * 50 * 128;
#pragma unroll
    for (int rg = 0; rg < 4; ++rg) {
      ez[rg] = __expf(xzv[rg] + az[rg] + brz);
      er[rg] = __expf(xrv[rg] + ar[rg] + brr);
      rh[rg] = ah[rg] + brh;
      float s1 = ez[rg], s2 = er[rg];
#pragma unroll
      for (int mm = 1; mm < 16; mm <<= 1) {
        s1 += __shfl_xor(s1, mm);
        s2 += __shfl_xor(s2, mm);
      }
      if (ccol == 0) {
        const int slot = role * 2 + ch;
        sb[slot * 128 + crow + rg] = s1;          // plain store -> L2
        sb[slot * 128 + 64 + crow + rg] = s2;
      }
    }
    bar_sync(flags, ++ep, tid, role);
    // ---- phase 2: reduce partials (L2-local), gates, h -> hTile -> 16B stores ----
    if (tid < 128) {
      float s = 0.f;
#pragma unroll
      for (int sl = 0; sl < 2 * NBLK; ++sl) s += sb[sl * 128 + tid];
      sSum[tid] = s;
    }
    __syncthreads();
#pragma unroll
    for (int rg = 0; rg < 4; ++rg) {
      int r = crow + rg;
      float z = ez[rg] / sSum[r];
      float rr2 = er[rg] / sSum[64 + r];
      float hh = tanhf(xhv[rg] + rr2 * rh[rg]);
      float hn = z * hfr[rg] + (1.f - z) * hh;
      hfr[rg] = hn;
      hTile[r * 32 + ch * 16 + ccol] = f2bf(hn);
    }
    __syncthreads();
    short* hCur = hSeq + (size_t)t * BB * HH;
    if (tid < 256) {
      int row = tid >> 2, seg = tid & 3;
      *(bf16x8*)(hCur + row * HH + c0 + seg * 8) = *(const bf16x8*)(hTile + row * 32 + seg * 8);
    }
    if (t + 1 < TT) {
#pragma unroll
      for (int rg = 0; rg < 4; ++rg) {   // prefetch next xg (overlaps the poll)
        const float* xrow = xg + ((size_t)(t + 1) * BB + crow + rg) * N3H;
        xzv[rg] = xrow[gcol];
        xrv[rg] = xrow[HH + gcol];
        xhv[rg] = xrow[2 * HH + gcol];
      }
    }
    bar_sync(flags, ++ep, tid, role);
  }
#pragma unroll
  for (int rg = 0; rg < 4; ++rg) hF[(crow + rg) * HH + gcol] = hfr[rg];
}

// -------- normalize pass: sum 500 per-row partials, scale row (exp already stored) --------
__global__ __launch_bounds__(256) void k_softmax(float* __restrict__ out,
                                                 const float* __restrict__ Pp) {
  float* row = out + (size_t)blockIdx.x * VV;
  const float* pp = Pp + (size_t)blockIdx.x * 512;
  const int tid = threadIdx.x;
  __shared__ float red[4];
  float sum = 0.f;
  for (int i = tid; i < 500; i += 256) sum += pp[i];
#pragma unroll
  for (int s = 32; s >= 1; s >>= 1) sum += __shfl_xor(sum, s);
  if ((tid & 63) == 0) red[tid >> 6] = sum;
  __syncthreads();
  float inv = 1.f / (red[0] + red[1] + red[2] + red[3]);
  for (int i = tid * 4; i < VV; i += 1024) {
    float4v v = *(const float4v*)(row + i);
    v[0] *= inv; v[1] *= inv; v[2] *= inv; v[3] *= inv;
    *(float4v*)(row + i) = v;
  }
}

extern "C" void kernel_launch(void* const* d_in, const int* in_sizes, int n_in,
                              void* d_out, int out_size, void* d_ws, size_t ws_size,
                              hipStream_t stream) {
  (void)in_sizes; (void)n_in; (void)out_size; (void)ws_size;
  const int*   enc  = (const int*)d_in[0];
  const int*   dec  = (const int*)d_in[1];
  const float* embF = (const float*)d_in[2];
  const float* Wd1  = (const float*)d_in[3];
  const float* bd1  = (const float*)d_in[4];
  const float* Wf1  = (const float*)d_in[5];
  const float* Uf1  = (const float*)d_in[6];
  const float* bf1  = (const float*)d_in[7];
  const float* Wf2  = (const float*)d_in[8];
  const float* Uf2  = (const float*)d_in[9];
  const float* bf2  = (const float*)d_in[10];
  const float* embE = (const float*)d_in[11];
  const float* We1  = (const float*)d_in[12];
  const float* Ue1  = (const float*)d_in[13];
  const float* be1  = (const float*)d_in[14];
  const float* We2  = (const float*)d_in[15];
  const float* Ue2  = (const float*)d_in[16];
  const float* be2  = (const float*)d_in[17];
  const float* Wout = (const float*)d_in[18];
  const float* bout = (const float*)d_in[19];

  char* p = (char*)d_ws;
  auto alloc = [&](size_t bytes) { char* r = p; p += (bytes + 255) & ~(size_t)255; return r; };
  short* WdT = (short*)alloc((size_t)896 * 800 * 2);
  short* WTb[4]; short* UTb[4];
  for (int i = 0; i < 4; ++i) {
    WTb[i] = (short*)alloc((size_t)2432 * 800 * 2);
    UTb[i] = (short*)alloc((size_t)2400 * 800 * 2);
  }
  short* WoT = (short*)alloc((size_t)VV * 800 * 2);
  short* feA = (short*)alloc((size_t)MR * DD * 2);
  short* fe  = (short*)alloc((size_t)MR * DD * 2);
  short* ee  = (short*)alloc((size_t)MR * DD * 2);
  short* g1  = (short*)alloc((size_t)MR * HH * 2);
  short* g2s = (short*)alloc((size_t)MR * HH * 2);   // layer-1 hSeq scratch
  short* e1  = (short*)alloc((size_t)MR * HH * 2);
  short* e2  = (short*)alloc((size_t)MR * HH * 2);
  float* xg  = (float*)alloc((size_t)MR * N3H * 4);
  float* Ppart = (float*)alloc((size_t)MR * 512 * 4);
  float* Spart = (float*)alloc((size_t)4 * TT * 50 * 128 * 4);  // per (layer,t)
  // --- zeroed-at-launch region: hF .. xreg ---
  float* hF   = (float*)alloc((size_t)BB * HH * 4);
  short* hIn0 = (short*)alloc((size_t)BB * HH * 2);
  int* flags  = (int*)alloc((size_t)NBLK * 16 * 4);
  int* xreg   = (int*)alloc((size_t)4 * 16 * 4);     // per-layer {cnt[8], winner}

  size_t tail = (char*)(xreg + 4 * 16) - (char*)hF;
  hipMemsetAsync(hF, 0, tail, stream);

  dim3 tb(32, 8);
  k_cast_transpose<<<dim3(25, 25), tb, 0, stream>>>(Wd1, WdT, 800, 800);
  const float* Ws[4] = {Wf1, Wf2, We1, We2};
  const float* Us[4] = {Uf1, Uf2, Ue1, Ue2};
  for (int i = 0; i < 4; ++i) {
    k_cast_transpose<<<dim3(75, 25), tb, 0, stream>>>(Ws[i], WTb[i], 800, 2400);
    k_cast_transpose<<<dim3(75, 25), tb, 0, stream>>>(Us[i], UTb[i], 800, 2400);
  }
  k_cast_transpose<<<dim3(1000, 25), tb, 0, stream>>>(Wout, WoT, 800, VV);
  k_gather<<<MR, 128, 0, stream>>>(enc, embF, feA);
  k_gather<<<MR, 128, 0, stream>>>(dec, embE, ee);
  // fe = relu(feA @ Wd1 + bd1)  -> bf16
  k_gemm<1><<<dim3(7, 24), 256, 0, stream>>>(feA, WdT, bd1, nullptr, fe, nullptr, 800, 800, 800);

  const float* bs[4] = {bf1, bf2, be1, be2};
  const short* Xs[4] = {fe, g1, ee, e1};
  short* hSeqL[4] = {g1, g2s, e1, e2};
  for (int l = 0; l < 4; ++l) {
    const short* hInit = (l == 0) ? hIn0 : hSeqL[l - 1] + (size_t)(TT - 1) * BB * HH;
    k_gemm<0><<<dim3(19, 24), 256, 0, stream>>>(Xs[l], WTb[l], bs[l], xg, nullptr, nullptr, N3H, 800, N3H);
    k_scan<<<256, 512, 0, stream>>>(xg, UTb[l], bs[l] + N3H, hF, hInit, hSeqL[l],
                                    Spart + (size_t)l * TT * 50 * 128,
                                    flags, l * 2 * TT, xreg + l * 16);
  }
  // out = exp(e2 @ Wout + bout) -> d_out (row-permuted to [B,T,V]) + row partials
  k_gemm<2><<<dim3(250, 24), 256, 0, stream>>>(e2, WoT, bout, (float*)d_out, nullptr, Ppart, VV, 800, VV);
  k_softmax<<<MR, 256, 0, stream>>>((float*)d_out, Ppart);
}

// Round 11
// 2368.840 us; speedup vs baseline: 1.6391x; 1.2178x over previous
//
#include <hip/hip_runtime.h>

#define DD 800
#define HH 800
#define BB 64
#define TT 48
#define N3H 2400
#define VV 32000
#define MR (TT*BB)   // 3072 rows, time-major (t*BB + b)
#define NBLK 25      // scan workers: 25 x 32 H-columns; blocks >= NBLK are GEMM helpers

typedef __attribute__((ext_vector_type(8))) short bf16x8;
typedef __attribute__((ext_vector_type(4))) float f32x4;
typedef __attribute__((ext_vector_type(4))) float float4v;
typedef __attribute__((address_space(1))) const unsigned int as1_uint;
typedef __attribute__((address_space(3))) unsigned int as3_uint;

__device__ __forceinline__ short f2bf(float f) {
  unsigned int u = __builtin_bit_cast(unsigned int, f);
  u = (u + 0x7fffu + ((u >> 16) & 1u)) >> 16;
  return (short)(unsigned short)u;
}

__device__ __forceinline__ void gload16(const void* g, void* l) {
  __builtin_amdgcn_global_load_lds((as1_uint*)g, (as3_uint*)l, 16, 0, 0);
}

// device-coherent 16B store: write-through to IC (visible chip-wide after vmcnt drain).
__device__ __forceinline__ void store16_cc(short* p, bf16x8 v) {
  asm volatile("global_store_dwordx4 %0, %1, off sc0 sc1" :: "v"(p), "v"(v));
}

// ---------------- transpose + cast fp32 [K][N] -> bf16 [N][K] ----------------
__global__ void k_cast_transpose(const float* __restrict__ src, short* __restrict__ dst,
                                 int K, int N) {
  __shared__ float tile[32][33];
  int n0 = blockIdx.x * 32, k0 = blockIdx.y * 32;
  int tx = threadIdx.x, ty = threadIdx.y;   // (32,8)
#pragma unroll
  for (int i = 0; i < 4; ++i) {
    int k = k0 + ty + i * 8, n = n0 + tx;
    if (k < K && n < N) tile[ty + i * 8][tx] = src[(size_t)k * N + n];
  }
  __syncthreads();
#pragma unroll
  for (int i = 0; i < 4; ++i) {
    int n = n0 + ty + i * 8, k = k0 + tx;
    if (n < N && k < K) dst[(size_t)n * K + k] = f2bf(tile[tx][ty + i * 8]);
  }
}

// ---------------- gather embedding rows -> bf16, time-major ----------------
__global__ void k_gather(const int* __restrict__ ids, const float* __restrict__ emb,
                         short* __restrict__ out) {
  int r = blockIdx.x;            // r = t*BB + b
  int t = r >> 6, b = r & 63;
  int id = ids[b * TT + t];
  int i = threadIdx.x;
  if (i < 100) {
    const float* s = emb + (size_t)id * DD + i * 8;
    float4v v0 = *(const float4v*)s;
    float4v v1 = *(const float4v*)(s + 4);
    bf16x8 o;
    o[0] = f2bf(v0[0]); o[1] = f2bf(v0[1]); o[2] = f2bf(v0[2]); o[3] = f2bf(v0[3]);
    o[4] = f2bf(v1[0]); o[5] = f2bf(v1[1]); o[6] = f2bf(v1[2]); o[7] = f2bf(v1[3]);
    *(bf16x8*)(out + (size_t)r * DD + i * 8) = o;
  }
}

// ---------------- standalone bf16 GEMM (prologue only) ----------------
// EPI 0: fp32 store + bias (xg).  EPI 1: relu -> bf16 (fe).
template <int EPI>
__global__ __launch_bounds__(256) void k_gemm(const short* __restrict__ A,
                                              const short* __restrict__ BT,
                                              const float* __restrict__ bias,
                                              float* __restrict__ Cf,
                                              short* __restrict__ Cb,
                                              int N, int K, int ldc) {
  __shared__ short lA[128 * 32];
  __shared__ short lB[128 * 32];
  const int tid = threadIdx.x, wid = tid >> 6, lane = tid & 63;
  const int m0 = blockIdx.y * 128, n0 = blockIdx.x * 128;
  const int wr = wid >> 1, wc = wid & 1;
  f32x4 acc[4][4] = {};
  for (int kt = 0; kt < K / 32; ++kt) {
    const int kb = kt * 32;
#pragma unroll
    for (int rr = 0; rr < 2; ++rr) {
      int s = rr * 256 + tid;
      gload16(A + (size_t)(m0 + (s >> 2)) * K + kb + (s & 3) * 8, (char*)lA + s * 16);
      gload16(BT + (size_t)(n0 + (s >> 2)) * K + kb + (s & 3) * 8, (char*)lB + s * 16);
    }
    __syncthreads();
    bf16x8 af[4], bfr[4];
#pragma unroll
    for (int i = 0; i < 4; ++i)
      af[i] = *(const bf16x8*)(lA + (wr * 64 + i * 16 + (lane & 15)) * 32 + (lane >> 4) * 8);
#pragma unroll
    for (int j = 0; j < 4; ++j)
      bfr[j] = *(const bf16x8*)(lB + (wc * 64 + j * 16 + (lane & 15)) * 32 + (lane >> 4) * 8);
#pragma unroll
    for (int i = 0; i < 4; ++i)
#pragma unroll
      for (int j = 0; j < 4; ++j)
        acc[i][j] = __builtin_amdgcn_mfma_f32_16x16x32_bf16(af[i], bfr[j], acc[i][j], 0, 0, 0);
    __syncthreads();
  }
  const int hi = lane >> 4, ccol = lane & 15;
#pragma unroll
  for (int i = 0; i < 4; ++i) {
    int row = m0 + wr * 64 + i * 16 + hi * 4;
#pragma unroll
    for (int j = 0; j < 4; ++j) {
      int col = n0 + wc * 64 + j * 16 + ccol;
      if (col >= N) continue;
      float bv = bias ? bias[col] : 0.f;
#pragma unroll
      for (int rg = 0; rg < 4; ++rg) {
        int r = row + rg;
        float v = acc[i][j][rg] + bv;
        if (EPI == 0) Cf[(size_t)r * ldc + col] = v;
        else          Cb[(size_t)r * ldc + col] = f2bf(v < 0.f ? 0.f : v);
      }
    }
  }
}

// ------- fence-free grid barrier (R7): flag-store arrive + 25-lane poll -------
__device__ __forceinline__ void bar_sync(int* flags, int ep, int tid) {
  asm volatile("s_waitcnt vmcnt(0)" ::: "memory");   // per-wave store drain
  __syncthreads();
  if (tid == 0)
    __hip_atomic_store(&flags[blockIdx.x * 32], ep, __ATOMIC_RELAXED, __HIP_MEMORY_SCOPE_AGENT);
  if (tid < 64) {
    bool ok;
    do {
      int v = ep;
      if (tid < NBLK)
        v = __hip_atomic_load(&flags[tid * 32], __ATOMIC_RELAXED, __HIP_MEMORY_SCOPE_AGENT);
      ok = __all(v - ep >= 0);
      if (!ok) __builtin_amdgcn_s_sleep(1);
    } while (!ok);
  }
  __syncthreads();
}

// ---------------- fused: persistent GRU scan (blocks 0..24) + helper GEMM ----------------
// Workers: exact R7 structure (best known). Helpers (blocks >= 25): ticketed 128x128
// bf16 GEMM over the NEXT layer's input; tile m needs scan steps <= 2m+1, enforced by
// polling the scan's flags (target pollBase + 2*tmax + 2). HEPI 0: fp32+bias (xg).
// HEPI 2: exp(v+bias) row-permuted to d_out + per-wave row partials (logits).
template <int HEPI>
__global__ __launch_bounds__(512, 1) void k_fused(
    const float* __restrict__ xg, const short* __restrict__ UT,
    const float* __restrict__ br, float* __restrict__ hF,
    const short* __restrict__ hInit, short* __restrict__ hSeq,
    float* __restrict__ Spart, int* __restrict__ flags, int ep0,
    const short* __restrict__ gA, const short* __restrict__ gBT,
    const float* __restrict__ gbias, float* __restrict__ gCf,
    float* __restrict__ gPp, int gN, int gldc, int gNT, int gNtiles,
    int* __restrict__ tcnt, int pollBase) {
  __shared__ __align__(16) char smem[159744];
  const int tid = threadIdx.x, wid = tid >> 6, lane = tid & 63;
  const int hi = lane >> 4, ccol = lane & 15;

  if (blockIdx.x < NBLK) {
    // ================= WORKER: R7 scan, verbatim =================
    short* uT    = (short*)smem;               // [96][808]
    float* sSum  = (float*)(smem + 155136);    // [128]
    short* hTile = (short*)(smem + 155648);    // [64][32]
    const int bid = blockIdx.x, c0 = bid * 32;
    const int rt = wid & 3, ch = wid >> 2;
    for (int idx = tid; idx < 96 * 100; idx += 512) {
      int rr = idx / 100, chk = idx % 100;
      int grow = (rr >> 5) * HH + c0 + (rr & 31);
      *(bf16x8*)(uT + rr * 808 + chk * 8) = *(const bf16x8*)(UT + (size_t)grow * HH + chk * 8);
    }
    const int crow = rt * 16 + hi * 4;
    const int gcol = c0 + ch * 16 + ccol;
    const int arow = rt * 16 + ccol;
    const short* uz = uT + (0 * 32 + ch * 16 + ccol) * 808;
    const short* ur = uT + (1 * 32 + ch * 16 + ccol) * 808;
    const short* uh = uT + (2 * 32 + ch * 16 + ccol) * 808;
    f32x4 hfr;
#pragma unroll
    for (int rg = 0; rg < 4; ++rg) hfr[rg] = hF[(crow + rg) * HH + gcol];
    const float brz = br[gcol], brr = br[HH + gcol], brh = br[2 * HH + gcol];
    int ep = ep0;
    float xzv[4], xrv[4], xhv[4];
#pragma unroll
    for (int rg = 0; rg < 4; ++rg) {
      const float* xrow = xg + ((size_t)(crow + rg)) * N3H;
      xzv[rg] = xrow[gcol];
      xrv[rg] = xrow[HH + gcol];
      xhv[rg] = xrow[2 * HH + gcol];
    }
    __syncthreads();

#pragma unroll 1
    for (int t = 0; t < TT; ++t) {
      const short* hPrev = (t == 0) ? hInit : hSeq + (size_t)(t - 1) * BB * HH;
      bf16x8 areg[25];
#pragma unroll
      for (int kt = 0; kt < 25; ++kt)
        areg[kt] = *(const bf16x8*)(hPrev + arow * HH + kt * 32 + hi * 8);
      f32x4 az = {}, ar = {}, ah = {};
#pragma unroll
      for (int kt = 0; kt < 25; ++kt) {
        const int o = kt * 32 + hi * 8;
        az = __builtin_amdgcn_mfma_f32_16x16x32_bf16(areg[kt], *(const bf16x8*)(uz + o), az, 0, 0, 0);
        ar = __builtin_amdgcn_mfma_f32_16x16x32_bf16(areg[kt], *(const bf16x8*)(ur + o), ar, 0, 0, 0);
        ah = __builtin_amdgcn_mfma_f32_16x16x32_bf16(areg[kt], *(const bf16x8*)(uh + o), ah, 0, 0, 0);
      }
      float ez[4], er[4], rh[4];
      float* sb = Spart + (size_t)t * 50 * 128;
#pragma unroll
      for (int rg = 0; rg < 4; ++rg) {
        ez[rg] = __expf(xzv[rg] + az[rg] + brz);
        er[rg] = __expf(xrv[rg] + ar[rg] + brr);
        rh[rg] = ah[rg] + brh;
        float s1 = ez[rg], s2 = er[rg];
#pragma unroll
        for (int mm = 1; mm < 16; mm <<= 1) {
          s1 += __shfl_xor(s1, mm);
          s2 += __shfl_xor(s2, mm);
        }
        if (ccol == 0) {
          const int slot = bid * 2 + ch;
          __hip_atomic_store(&sb[slot * 128 + crow + rg], s1, __ATOMIC_RELAXED, __HIP_MEMORY_SCOPE_AGENT);
          __hip_atomic_store(&sb[slot * 128 + 64 + crow + rg], s2, __ATOMIC_RELAXED, __HIP_MEMORY_SCOPE_AGENT);
        }
      }
      bar_sync(flags, ++ep, tid);
      if (tid < 128) {
        float s = 0.f;
#pragma unroll
        for (int sl = 0; sl < 2 * NBLK; ++sl)
          s += __hip_atomic_load(&sb[sl * 128 + tid], __ATOMIC_RELAXED, __HIP_MEMORY_SCOPE_AGENT);
        sSum[tid] = s;
      }
      __syncthreads();
#pragma unroll
      for (int rg = 0; rg < 4; ++rg) {
        int r = crow + rg;
        float z = ez[rg] / sSum[r];
        float rr2 = er[rg] / sSum[64 + r];
        float hh = tanhf(xhv[rg] + rr2 * rh[rg]);
        float hn = z * hfr[rg] + (1.f - z) * hh;
        hfr[rg] = hn;
        hTile[r * 32 + ch * 16 + ccol] = f2bf(hn);
      }
      __syncthreads();
      short* hCur = hSeq + (size_t)t * BB * HH;
      if (tid < 256) {
        int row = tid >> 2, seg = tid & 3;
        store16_cc(hCur + row * HH + c0 + seg * 8, *(const bf16x8*)(hTile + row * 32 + seg * 8));
      }
      if (t + 1 < TT) {
#pragma unroll
        for (int rg = 0; rg < 4; ++rg) {
          const float* xrow = xg + ((size_t)(t + 1) * BB + crow + rg) * N3H;
          xzv[rg] = xrow[gcol];
          xrv[rg] = xrow[HH + gcol];
          xhv[rg] = xrow[2 * HH + gcol];
        }
      }
      bar_sync(flags, ++ep, tid);
    }
#pragma unroll
    for (int rg = 0; rg < 4; ++rg) hF[(crow + rg) * HH + gcol] = hfr[rg];
    return;
  }

  // ================= HELPER: ticketed 128x128 GEMM, 8 waves/tile =================
  short* lA = (short*)smem;
  short* lB = (short*)(smem + 8192);
  int*   tk = (int*)(smem + 16384);
  const int wr = wid >> 1, wc = wid & 1;
  for (;;) {
    if (tid == 0)
      tk[0] = __hip_atomic_fetch_add(tcnt, 1, __ATOMIC_RELAXED, __HIP_MEMORY_SCOPE_AGENT);
    __syncthreads();
    const int t0 = tk[0];
    if (t0 >= gNtiles) break;          // uniform across block
    const int mb = t0 / gNT, nb = t0 % gNT;
    const int m0 = mb * 128, n0 = nb * 128;
    // poll: rows of tile mb are final once scan step 2*mb+1 is published
    {
      int tmax = 2 * mb + 1; if (tmax > TT - 1) tmax = TT - 1;
      const int ft = pollBase + 2 * tmax + 2;
      bool ok;
      do {
        int v = ft;
        if (lane < NBLK)
          v = __hip_atomic_load(&flags[lane * 32], __ATOMIC_RELAXED, __HIP_MEMORY_SCOPE_AGENT);
        ok = __all(v - ft >= 0);
        if (!ok) __builtin_amdgcn_s_sleep(2);
      } while (!ok);
      asm volatile("" ::: "memory");
    }
    f32x4 acc[2][4] = {};
    const int srow = tid >> 2, sseg = tid & 3;
    for (int kt = 0; kt < 25; ++kt) {
      const int kb = kt * 32;
      gload16(gA + (size_t)(m0 + srow) * 800 + kb + sseg * 8, (char*)lA + tid * 16);
      gload16(gBT + (size_t)(n0 + srow) * 800 + kb + sseg * 8, (char*)lB + tid * 16);
      __syncthreads();
      bf16x8 af[2], bf[4];
#pragma unroll
      for (int i = 0; i < 2; ++i)
        af[i] = *(const bf16x8*)(lA + (wr * 32 + i * 16 + (lane & 15)) * 32 + hi * 8);
#pragma unroll
      for (int j = 0; j < 4; ++j)
        bf[j] = *(const bf16x8*)(lB + (wc * 64 + j * 16 + (lane & 15)) * 32 + hi * 8);
#pragma unroll
      for (int i = 0; i < 2; ++i)
#pragma unroll
        for (int j = 0; j < 4; ++j)
          acc[i][j] = __builtin_amdgcn_mfma_f32_16x16x32_bf16(af[i], bf[j], acc[i][j], 0, 0, 0);
      __syncthreads();
    }
    if (HEPI == 2) {
#pragma unroll
      for (int i = 0; i < 2; ++i) {
        int row = m0 + wr * 32 + i * 16 + hi * 4;
#pragma unroll
        for (int rg = 0; rg < 4; ++rg) {
          int r = row + rg;
          int orow = (r & 63) * TT + (r >> 6);   // (t,b) -> (b,t)
          float part = 0.f;
#pragma unroll
          for (int j = 0; j < 4; ++j) {
            int col = n0 + wc * 64 + j * 16 + ccol;
            float v = __expf(acc[i][j][rg] + gbias[col]);
            part += v;
            gCf[(size_t)orow * gldc + col] = v;
          }
#pragma unroll
          for (int mm = 1; mm < 16; mm <<= 1) part += __shfl_xor(part, mm);
          if (ccol == 0) gPp[(size_t)orow * 512 + nb * 2 + wc] = part;
        }
      }
    } else {
#pragma unroll
      for (int i = 0; i < 2; ++i) {
        int row = m0 + wr * 32 + i * 16 + hi * 4;
#pragma unroll
        for (int j = 0; j < 4; ++j) {
          int col = n0 + wc * 64 + j * 16 + ccol;
          if (col >= gN) continue;
          float bv = gbias[col];
#pragma unroll
          for (int rg = 0; rg < 4; ++rg)
            gCf[(size_t)(row + rg) * gldc + col] = acc[i][j][rg] + bv;
        }
      }
    }
  }
}

// -------- normalize pass: sum 500 per-row partials, scale row (exp already stored) --------
__global__ __launch_bounds__(256) void k_softmax(float* __restrict__ out,
                                                 const float* __restrict__ Pp) {
  float* row = out + (size_t)blockIdx.x * VV;
  const float* pp = Pp + (size_t)blockIdx.x * 512;
  const int tid = threadIdx.x;
  __shared__ float red[4];
  float sum = 0.f;
  for (int i = tid; i < 500; i += 256) sum += pp[i];
#pragma unroll
  for (int s = 32; s >= 1; s >>= 1) sum += __shfl_xor(sum, s);
  if ((tid & 63) == 0) red[tid >> 6] = sum;
  __syncthreads();
  float inv = 1.f / (red[0] + red[1] + red[2] + red[3]);
  for (int i = tid * 4; i < VV; i += 1024) {
    float4v v = *(const float4v*)(row + i);
    v[0] *= inv; v[1] *= inv; v[2] *= inv; v[3] *= inv;
    *(float4v*)(row + i) = v;
  }
}

extern "C" void kernel_launch(void* const* d_in, const int* in_sizes, int n_in,
                              void* d_out, int out_size, void* d_ws, size_t ws_size,
                              hipStream_t stream) {
  (void)in_sizes; (void)n_in; (void)out_size; (void)ws_size;
  const int*   enc  = (const int*)d_in[0];
  const int*   dec  = (const int*)d_in[1];
  const float* embF = (const float*)d_in[2];
  const float* Wd1  = (const float*)d_in[3];
  const float* bd1  = (const float*)d_in[4];
  const float* Wf1  = (const float*)d_in[5];
  const float* Uf1  = (const float*)d_in[6];
  const float* bf1  = (const float*)d_in[7];
  const float* Wf2  = (const float*)d_in[8];
  const float* Uf2  = (const float*)d_in[9];
  const float* bf2  = (const float*)d_in[10];
  const float* embE = (const float*)d_in[11];
  const float* We1  = (const float*)d_in[12];
  const float* Ue1  = (const float*)d_in[13];
  const float* be1  = (const float*)d_in[14];
  const float* We2  = (const float*)d_in[15];
  const float* Ue2  = (const float*)d_in[16];
  const float* be2  = (const float*)d_in[17];
  const float* Wout = (const float*)d_in[18];
  const float* bout = (const float*)d_in[19];

  char* p = (char*)d_ws;
  auto alloc = [&](size_t bytes) { char* r = p; p += (bytes + 255) & ~(size_t)255; return r; };
  short* WdT = (short*)alloc((size_t)896 * 800 * 2);
  short* WTb[4]; short* UTb[4];
  for (int i = 0; i < 4; ++i) {
    WTb[i] = (short*)alloc((size_t)2432 * 800 * 2);
    UTb[i] = (short*)alloc((size_t)2400 * 800 * 2);
  }
  short* WoT = (short*)alloc((size_t)VV * 800 * 2);
  short* feA = (short*)alloc((size_t)MR * DD * 2);
  short* fe  = (short*)alloc((size_t)MR * DD * 2);
  short* ee  = (short*)alloc((size_t)MR * DD * 2);
  short* g1  = (short*)alloc((size_t)MR * HH * 2);
  short* g2s = (short*)alloc((size_t)MR * HH * 2);   // layer-1 hSeq scratch
  short* e1  = (short*)alloc((size_t)MR * HH * 2);
  short* e2  = (short*)alloc((size_t)MR * HH * 2);
  float* xgA = (float*)alloc((size_t)MR * N3H * 4);
  float* xgB = (float*)alloc((size_t)MR * N3H * 4);
  float* Ppart = (float*)alloc((size_t)MR * 512 * 4);
  float* Spart = (float*)alloc((size_t)TT * 50 * 128 * 4);
  // --- zeroed-at-launch region: hF .. tcnt ---
  float* hF   = (float*)alloc((size_t)BB * HH * 4);
  short* hIn0 = (short*)alloc((size_t)BB * HH * 2);
  int* flags  = (int*)alloc((size_t)NBLK * 32 * 4);
  int* tcnt   = (int*)alloc((size_t)16 * 4);

  size_t tail = (char*)(tcnt + 16) - (char*)hF;
  hipMemsetAsync(hF, 0, tail, stream);

  dim3 tb(32, 8);
  k_cast_transpose<<<dim3(25, 25), tb, 0, stream>>>(Wd1, WdT, 800, 800);
  const float* Ws[4] = {Wf1, Wf2, We1, We2};
  const float* Us[4] = {Uf1, Uf2, Ue1, Ue2};
  for (int i = 0; i < 4; ++i) {
    k_cast_transpose<<<dim3(75, 25), tb, 0, stream>>>(Ws[i], WTb[i], 800, 2400);
    k_cast_transpose<<<dim3(75, 25), tb, 0, stream>>>(Us[i], UTb[i], 800, 2400);
  }
  k_cast_transpose<<<dim3(1000, 25), tb, 0, stream>>>(Wout, WoT, 800, VV);
  k_gather<<<MR, 128, 0, stream>>>(enc, embF, feA);
  k_gather<<<MR, 128, 0, stream>>>(dec, embE, ee);
  // fe = relu(feA @ Wd1 + bd1) -> bf16 ; then xgF1 = fe @ Wf1 + bf1[0] -> xgA
  k_gemm<1><<<dim3(7, 24), 256, 0, stream>>>(feA, WdT, bd1, nullptr, fe, 800, 800, 800);
  k_gemm<0><<<dim3(19, 24), 256, 0, stream>>>(fe, WTb[0], bf1, xgA, nullptr, N3H, 800, N3H);

  const float* bs[4] = {bf1, bf2, be1, be2};
  short* hSeqL[4] = {g1, g2s, e1, e2};
  float* xgR[4] = {xgA, xgB, xgA, xgB};      // scan l reads
  // helper during scan l computes layer l+1's xg (or logits at l=3)
  const short* hA[4]   = {g1, ee, e1, e2};
  const short* hBT[4]  = {WTb[1], WTb[2], WTb[3], WoT};
  const float* hBias[4]= {bs[1], bs[2], bs[3], bout};
  float* hOut[4] = {xgB, xgA, xgB, (float*)d_out};
  int   hPoll[4] = {0 * 96, -1000000, 2 * 96, 3 * 96};   // l=1 input (ee) needs no poll

  for (int l = 0; l < 4; ++l) {
    const short* hInit = (l == 0) ? hIn0 : hSeqL[l - 1] + (size_t)(TT - 1) * BB * HH;
    if (l < 3) {
      k_fused<0><<<256, 512, 0, stream>>>(xgR[l], UTb[l], bs[l] + N3H, hF, hInit, hSeqL[l],
                                          Spart, flags, l * 2 * TT,
                                          hA[l], hBT[l], hBias[l], hOut[l], nullptr,
                                          N3H, N3H, 19, 24 * 19, &tcnt[l], hPoll[l]);
    } else {
      k_fused<2><<<256, 512, 0, stream>>>(xgR[l], UTb[l], bs[l] + N3H, hF, hInit, hSeqL[l],
                                          Spart, flags, l * 2 * TT,
                                          hA[l], hBT[l], hBias[l], hOut[l], Ppart,
                                          VV, VV, 250, 24 * 250, &tcnt[l], hPoll[l]);
    }
  }
  k_softmax<<<MR, 256, 0, stream>>>((float*)d_out, Ppart);
}